// Round 5
// baseline (2174.506 us; speedup 1.0000x reference)
//
#include <hip/hip_runtime.h>
#include <hip/hip_bf16.h>

typedef _Float16 h16;
typedef _Float16 f16x8 __attribute__((ext_vector_type(8)));
typedef _Float16 f16x4 __attribute__((ext_vector_type(4)));
typedef float f32x4 __attribute__((ext_vector_type(4)));

#define SEGS 32
#define LCTX 512
#define RQ 64
#define NH 32
#define HDIM 128
#define DMODEL 4096

// ---------------- cast fp32 -> fp16 (row-major preserved) ----------------
__global__ __launch_bounds__(256) void cast_f16_kernel(const float* __restrict__ in,
                                                       h16* __restrict__ out) {
    long i = ((long)blockIdx.x * 256 + threadIdx.x) * 4;
    float4 f = *(const float4*)&in[i];
    f16x4 o;
    o[0] = (h16)f.x; o[1] = (h16)f.y; o[2] = (h16)f.z; o[3] = (h16)f.w;
    *(f16x4*)&out[i] = o;
}

// ---------------- transpose + cast: in[K][N] fp32 -> out[N][K] fp16 ----------------
__global__ __launch_bounds__(256) void transpose_cast_kernel(const float* __restrict__ in,
                                                             h16* __restrict__ out,
                                                             int K, int N) {
    __shared__ float tile[32][33];
    int bx = blockIdx.x;  // tiles along N
    int by = blockIdx.y;  // tiles along K
    int tx = threadIdx.x & 31, ty = threadIdx.x >> 5;  // ty 0..7
#pragma unroll
    for (int j = 0; j < 4; j++)
        tile[ty + j * 8][tx] = in[(long)(by * 32 + ty + j * 8) * N + bx * 32 + tx];
    __syncthreads();
#pragma unroll
    for (int j = 0; j < 4; j++)
        out[(long)(bx * 32 + ty + j * 8) * K + by * 32 + tx] = (h16)tile[tx][ty + j * 8];
}

// ---------------- pooling (mean of 8 rows) + rmsnorm -> queries fp32, qn fp16 ----------------
__global__ __launch_bounds__(256) void pool_rms_kernel(const float* __restrict__ x,
                                                       const float* __restrict__ wnorm,
                                                       float* __restrict__ queries,
                                                       h16* __restrict__ qn) {
    const int qi = blockIdx.x;      // 0..2047
    const int t = threadIdx.x;
    const long base = (long)qi * 8 * DMODEL;
    float v[16];
    float ss = 0.f;
#pragma unroll
    for (int i = 0; i < 16; i++) {
        int col = t + i * 256;
        float s = 0.f;
#pragma unroll
        for (int r = 0; r < 8; r++) s += x[base + (long)r * DMODEL + col];
        v[i] = s * 0.125f;
        ss += v[i] * v[i];
    }
#pragma unroll
    for (int d = 1; d < 64; d <<= 1) ss += __shfl_xor(ss, d, 64);
    __shared__ float red[4];
    if ((t & 63) == 0) red[t >> 6] = ss;
    __syncthreads();
    float tot = red[0] + red[1] + red[2] + red[3];
    float scale = rsqrtf(tot / (float)DMODEL + 1e-5f);
#pragma unroll
    for (int i = 0; i < 16; i++) {
        int col = t + i * 256;
        queries[(long)qi * DMODEL + col] = v[i];
        qn[(long)qi * DMODEL + col] = (h16)(v[i] * scale * wnorm[col]);
    }
}

// ============== 256x256x64 8-wave GEMM: C[M][N] = A[M][K] @ Bt[N][K]^T ==============
// fp16 in, MFMA 16x16x32, fp32 acc. EPI==0: fp16 C. EPI==1: fp32 C + residual.
// 4 phases per K-tile, double-buffered 128KiB LDS, global_load_lds dwordx4 staging with
// both-sides XOR swizzle (byte bits 5,6 ^= bits 9,10). ALL 8 next-tile prefetch loads
// are issued at phase 0 (the target buffer is fully consumed by then), giving >=3-phase
// latency cover before the counted tail waits. vmcnt never drains to 0 in the hot loop;
// the last tile is peeled and drains with vmcnt(0) at phase 1.
//
// vmcnt ledger (per wave, issue-order oldest-first):
//   entry: 2 outstanding (current tile's A-l1 pair)
//   ph0: +8 (next tile's B0,B1,B2,B3,Al0a,Al0b,Al1a,Al1b) -> 10
//   ph1 tail vmcnt(8): retires cur A-l1 (2 oldest) -> 8   [ph2/3 read A-l1]
//   ph3 tail vmcnt(2): retires next B(4)+A-l0(2)   -> 2   [next LOADB/ph0/ph1 read them]

__device__ __forceinline__ void g2l16(const h16* g, char* l) {
    __builtin_amdgcn_global_load_lds(
        (const __attribute__((address_space(1))) unsigned int*)g,
        (__attribute__((address_space(3))) unsigned int*)l, 16, 0, 0);
}

#define MFMA(d, va, vb) d = __builtin_amdgcn_mfma_f32_16x16x32_f16(va, vb, d, 0, 0, 0)

// One phase: 4 A-frag ds_reads, optional stage, barrier, wait, 16 MFMA, tail wait, barrier.
#define GPHASE(OFF0, OFF1, MI0, MI1, STAGE_STMT, TAIL)                           \
    a0 = *(const f16x8*)(smem + ao + (OFF0) + kf0);                              \
    a1 = *(const f16x8*)(smem + ao + (OFF0) + kf1);                              \
    a2 = *(const f16x8*)(smem + ao + (OFF1) + kf0);                              \
    a3 = *(const f16x8*)(smem + ao + (OFF1) + kf1);                              \
    STAGE_STMT;                                                                  \
    __builtin_amdgcn_s_barrier();                                                \
    asm volatile("s_waitcnt lgkmcnt(0)" ::: "memory");                           \
    __builtin_amdgcn_sched_barrier(0);                                           \
    __builtin_amdgcn_s_setprio(1);                                               \
    MFMA(acc[MI0][0], a0, b00); MFMA(acc[MI1][0], a2, b00);                      \
    MFMA(acc[MI0][1], a0, b10); MFMA(acc[MI1][1], a2, b10);                      \
    MFMA(acc[MI0][2], a0, b20); MFMA(acc[MI1][2], a2, b20);                      \
    MFMA(acc[MI0][3], a0, b30); MFMA(acc[MI1][3], a2, b30);                      \
    MFMA(acc[MI0][0], a1, b01); MFMA(acc[MI1][0], a3, b01);                      \
    MFMA(acc[MI0][1], a1, b11); MFMA(acc[MI1][1], a3, b11);                      \
    MFMA(acc[MI0][2], a1, b21); MFMA(acc[MI1][2], a3, b21);                      \
    MFMA(acc[MI0][3], a1, b31); MFMA(acc[MI1][3], a3, b31);                      \
    __builtin_amdgcn_s_setprio(0);                                               \
    TAIL;                                                                        \
    __builtin_amdgcn_s_barrier();                                                \
    __builtin_amdgcn_sched_barrier(0)

#define LOADB(bb)                                                                \
    b00 = *(const f16x8*)(smem + (bb) + 0    + kf0);                             \
    b01 = *(const f16x8*)(smem + (bb) + 0    + kf1);                             \
    b10 = *(const f16x8*)(smem + (bb) + 2048 + kf0);                             \
    b11 = *(const f16x8*)(smem + (bb) + 2048 + kf1);                             \
    b20 = *(const f16x8*)(smem + (bb) + 4096 + kf0);                             \
    b21 = *(const f16x8*)(smem + (bb) + 4096 + kf1);                             \
    b30 = *(const f16x8*)(smem + (bb) + 6144 + kf0);                             \
    b31 = *(const f16x8*)(smem + (bb) + 6144 + kf1)

// issue ALL 8 prefetch loads for the next tile (buffer po is dead by phase 0)
#define STAGE8()                                                                 \
    do { g2l16(gp0, smem + po + lo0); gp0 += 64;                                 \
         g2l16(gp1, smem + po + lo1); gp1 += 64;                                 \
         g2l16(gp2, smem + po + lo2); gp2 += 64;                                 \
         g2l16(gp3, smem + po + lo3); gp3 += 64;                                 \
         g2l16(gp4, smem + po + lo4); gp4 += 64;                                 \
         g2l16(gp5, smem + po + lo5); gp5 += 64;                                 \
         g2l16(gp6, smem + po + lo6); gp6 += 64;                                 \
         g2l16(gp7, smem + po + lo7); gp7 += 64; } while (0)

__global__ __launch_bounds__(512, 2) void gemm256_kernel(
    const h16* __restrict__ A, const h16* __restrict__ Bt,
    h16* __restrict__ Ch, float* __restrict__ Cf, const float* __restrict__ res,
    int M, int N, int K, int EPI) {
    __shared__ __align__(16) char smem[131072];   // [buf2][A 32K | B 32K]

    const int t = threadIdx.x;
    const int lane = t & 63, w = t >> 6;
    const int wm = w >> 2, wn = w & 3;            // 2 x 4 wave grid
    const int row16 = lane & 15, kq = lane >> 4;

    // XCD-bijective swizzle (grids here are multiples of 8)
    const int nwg = gridDim.x;
    const int id = blockIdx.x;
    const int swz = (id & 7) * (nwg >> 3) + (id >> 3);
    const int NBX = N >> 8;
    const int by = swz / NBX, bx = swz % NBX;
    const long byM = (long)by * 256, bxN = (long)bx * 256;

    // ds-read side swizzle: flip byte bits 5,6 by row bits 2,3
    const unsigned X = ((row16 & 4) ? 32u : 0u) | ((row16 & 8) ? 64u : 0u);
    const unsigned kf0 = (kq * 16) ^ X;           // kstep 0
    const unsigned kf1 = (64 + kq * 16) ^ X;      // kstep 1
    const unsigned aBase = wm * 16384 + row16 * 128;
    const unsigned bBase = 32768u + (wn >> 1) * 16384 + (wn & 1) * 8192 + row16 * 128;

    // staging: per-thread pre-swizzled global source; linear LDS dest (wave-uniform base)
    const unsigned t16x = (unsigned)(t * 16) ^ ((t & 32) ? 32u : 0u) ^ ((t & 64) ? 64u : 0u);
    const int rl = (int)(t16x >> 7);              // row within 64-row load block
    const int chh = (int)((t16x & 127) >> 1);     // h16 col (multiple of 8)
    // slot order (issue order = need order): B h0l0, B h0l1, B h1l0, B h1l1,
    //                                        A l0a, A l0b, A l1a, A l1b
    const h16* gp0 = Bt + (bxN +   0 + rl) * K + chh;
    const h16* gp1 = Bt + (bxN +  64 + rl) * K + chh;
    const h16* gp2 = Bt + (bxN + 128 + rl) * K + chh;
    const h16* gp3 = Bt + (bxN + 192 + rl) * K + chh;
    const h16* gp4 = A  + (byM +   0 + rl) * K + chh;
    const h16* gp5 = A  + (byM + 128 + rl) * K + chh;
    const h16* gp6 = A  + (byM +  64 + rl) * K + chh;
    const h16* gp7 = A  + (byM + 192 + rl) * K + chh;
    const unsigned wb = (unsigned)w * 1024;
    const unsigned lo0 = 32768u + wb,         lo1 = 32768u + 8192 + wb;
    const unsigned lo2 = 49152u + wb,         lo3 = 49152u + 8192 + wb;
    const unsigned lo4 = wb,                  lo5 = 16384u + wb;
    const unsigned lo6 = 8192u + wb,          lo7 = 24576u + wb;

    // prologue: stage tile 0 into buf0; retire all but the 2 newest (A l1 slots)
    g2l16(gp0, smem + lo0); gp0 += 64;
    g2l16(gp1, smem + lo1); gp1 += 64;
    g2l16(gp2, smem + lo2); gp2 += 64;
    g2l16(gp3, smem + lo3); gp3 += 64;
    g2l16(gp4, smem + lo4); gp4 += 64;
    g2l16(gp5, smem + lo5); gp5 += 64;
    g2l16(gp6, smem + lo6); gp6 += 64;
    g2l16(gp7, smem + lo7); gp7 += 64;
    asm volatile("s_waitcnt vmcnt(2)" ::: "memory");
    __builtin_amdgcn_s_barrier();
    __builtin_amdgcn_sched_barrier(0);

    f32x4 acc[8][4] = {};
    const int NT = K >> 6;
    // hot loop: tiles 0 .. NT-2, prefetching tile tt+1 entirely at phase 0.
    for (int tt = 0; tt < NT - 1; ++tt) {
        const unsigned bo = (tt & 1) ? 65536u : 0u;
        const unsigned po = 65536u - bo;
        const unsigned ao = bo + aBase;
        f16x8 a0, a1, a2, a3;
        f16x8 b00, b01, b10, b11, b20, b21, b30, b31;
        LOADB(bo + bBase);
        // phase 0: A rows 0-31   | issue ALL next-tile prefetch
        GPHASE(0,     2048,  0, 1, STAGE8(), (void)0);
        // phase 1: A rows 32-63  | vmcnt(8): cur A-l1 landed (needed ph2/3)
        GPHASE(4096,  6144,  2, 3, (void)0,
               asm volatile("s_waitcnt vmcnt(8)" ::: "memory"));
        // phase 2: A rows 64-95
        GPHASE(8192,  10240, 4, 5, (void)0, (void)0);
        // phase 3: A rows 96-127 | vmcnt(2): next tile's B + A-l0 landed
        GPHASE(12288, 14336, 6, 7, (void)0,
               asm volatile("s_waitcnt vmcnt(2)" ::: "memory"));
    }
    // peeled last tile: no prefetch. Entry outstanding = 2 (this tile's A-l1): the
    // phase-1 tail MUST be vmcnt(0) (a counted wait would be an immediate no-op -> race).
    {
        const unsigned bo = ((NT - 1) & 1) ? 65536u : 0u;
        const unsigned ao = bo + aBase;
        f16x8 a0, a1, a2, a3;
        f16x8 b00, b01, b10, b11, b20, b21, b30, b31;
        LOADB(bo + bBase);
        GPHASE(0,     2048,  0, 1, (void)0, (void)0);
        GPHASE(4096,  6144,  2, 3, (void)0,
               asm volatile("s_waitcnt vmcnt(0)" ::: "memory"));
        GPHASE(8192,  10240, 4, 5, (void)0, (void)0);
        GPHASE(12288, 14336, 6, 7, (void)0, (void)0);
    }

    // epilogue: C/D layout row = quad*4+reg, col = lane&15
    const long wrow = byM + wm * 128 + (lane >> 4) * 4;
    const long wcol = bxN + wn * 64 + row16;
#pragma unroll
    for (int mi = 0; mi < 8; mi++)
#pragma unroll
        for (int n = 0; n < 4; n++)
#pragma unroll
            for (int r = 0; r < 4; r++) {
                long idx = (wrow + mi * 16 + r) * N + wcol + n * 16;
                float v = acc[mi][n][r];
                if (EPI == 0) Ch[idx] = (h16)v;
                else          Cf[idx] = v + res[idx];
            }
}

// ---------------- flash attention: one block per (seg, head) ----------------
// q[2048][4096] fp16, kv[16384][8192] fp16 (k cols 0..4095, v cols 4096..8191)
__global__ __launch_bounds__(256) void attn_kernel(const h16* __restrict__ q,
                                                   const h16* __restrict__ kv,
                                                   h16* __restrict__ o) {
    const int h = blockIdx.x;   // 0..31
    const int s = blockIdx.y;   // 0..31
    const int t = threadIdx.x;
    const int lane = t & 63, w = t >> 6;
    const int row16 = lane & 15, quad = lane >> 4;

    __shared__ h16 kls[32][HDIM + 8];      // [kcol][hd]
    __shared__ h16 vls[HDIM][32 + 8];      // [hd][kcol] (transposed)
    __shared__ h16 pls[4][16][32 + 8];     // per-wave P tile

    f16x8 qf[4];
    {
        const long qrow = (long)(s * RQ + w * 16 + row16) * DMODEL + h * HDIM;
#pragma unroll
        for (int f = 0; f < 4; f++) qf[f] = *(const f16x8*)&q[qrow + f * 32 + quad * 8];
    }
    const float sc = 0.08838834764831845f;  // 1/sqrt(128)
    f32x4 oacc[8] = {};
    float m_i[4], l_i[4];
#pragma unroll
    for (int r = 0; r < 4; r++) { m_i[r] = -1e30f; l_i[r] = 0.f; }

    const long kvbase = (long)s * LCTX * 8192 + h * HDIM;

    for (int kc = 0; kc < LCTX; kc += 32) {
#pragma unroll
        for (int p = 0; p < 2; p++) {
            int u = t + p * 256;
            int r = u >> 4;            // 0..31
            int c8 = (u & 15) * 8;     // 0..120
            *(uint4*)&kls[r][c8] = *(const uint4*)&kv[kvbase + (long)(kc + r) * 8192 + c8];
            f16x8 vv = *(const f16x8*)&kv[kvbase + 4096 + (long)(kc + r) * 8192 + c8];
#pragma unroll
            for (int j = 0; j < 8; j++) vls[c8 + j][r] = vv[j];
        }
        __syncthreads();

        f32x4 st[2] = {};
#pragma unroll
        for (int ct = 0; ct < 2; ct++)
#pragma unroll
            for (int f = 0; f < 4; f++) {
                f16x8 bk = *(const f16x8*)&kls[ct * 16 + row16][f * 32 + quad * 8];
                st[ct] = __builtin_amdgcn_mfma_f32_16x16x32_f16(qf[f], bk, st[ct], 0, 0, 0);
            }

#pragma unroll
        for (int r = 0; r < 4; r++) {
            float s0 = st[0][r] * sc, s1 = st[1][r] * sc;
            float mx = fmaxf(s0, s1);
#pragma unroll
            for (int d = 1; d < 16; d <<= 1) mx = fmaxf(mx, __shfl_xor(mx, d, 64));
            float mn = fmaxf(m_i[r], mx);
            float al = __expf(m_i[r] - mn);
            float p0 = __expf(s0 - mn), p1 = __expf(s1 - mn);
            float ps = p0 + p1;
#pragma unroll
            for (int d = 1; d < 16; d <<= 1) ps += __shfl_xor(ps, d, 64);
            l_i[r] = l_i[r] * al + ps;
            m_i[r] = mn;
#pragma unroll
            for (int ht = 0; ht < 8; ht++) oacc[ht][r] *= al;
            pls[w][quad * 4 + r][row16]      = (h16)p0;
            pls[w][quad * 4 + r][16 + row16] = (h16)p1;
        }
        f16x8 pa = *(const f16x8*)&pls[w][row16][quad * 8];
#pragma unroll
        for (int ht = 0; ht < 8; ht++) {
            f16x8 bv = *(const f16x8*)&vls[ht * 16 + row16][quad * 8];
            oacc[ht] = __builtin_amdgcn_mfma_f32_16x16x32_f16(pa, bv, oacc[ht], 0, 0, 0);
        }
        __syncthreads();
    }
#pragma unroll
    for (int r = 0; r < 4; r++) {
        float inv = 1.0f / l_i[r];
        long orow = (long)(s * RQ + w * 16 + quad * 4 + r) * DMODEL + h * HDIM;
#pragma unroll
        for (int ht = 0; ht < 8; ht++) o[orow + ht * 16 + row16] = (h16)(oacc[ht][r] * inv);
    }
}

// ---------------- final rmsnorm ----------------
__global__ __launch_bounds__(256) void final_rms_kernel(const float* __restrict__ tmp,
                                                        const float* __restrict__ w,
                                                        float* __restrict__ out) {
    const int row = blockIdx.x;
    const int t = threadIdx.x;
    float v[16];
    float ss = 0.f;
#pragma unroll
    for (int i = 0; i < 16; i++) {
        v[i] = tmp[(long)row * DMODEL + t + i * 256];
        ss += v[i] * v[i];
    }
#pragma unroll
    for (int d = 1; d < 64; d <<= 1) ss += __shfl_xor(ss, d, 64);
    __shared__ float red[4];
    if ((t & 63) == 0) red[t >> 6] = ss;
    __syncthreads();
    float tot = red[0] + red[1] + red[2] + red[3];
    float scale = rsqrtf(tot / (float)DMODEL + 1e-5f);
#pragma unroll
    for (int i = 0; i < 16; i++) {
        int col = t + i * 256;
        out[(long)row * DMODEL + col] = v[i] * scale * w[col];
    }
}

extern "C" void kernel_launch(void* const* d_in, const int* in_sizes, int n_in,
                              void* d_out, int out_size, void* d_ws, size_t ws_size,
                              hipStream_t stream) {
    const float* x      = (const float*)d_in[0];  // [16384][4096]
    const float* anw    = (const float*)d_in[1];  // [4096]
    const float* wq     = (const float*)d_in[2];  // [4096][4096]
    const float* wkv    = (const float*)d_in[3];  // [4096][8192]
    const float* wo     = (const float*)d_in[4];  // [4096][4096]
    const float* onw    = (const float*)d_in[5];  // [4096]
    float* out          = (float*)d_out;          // [2048][4096]

    size_t off = 0;
    auto carve = [&](size_t bytes) {
        void* p = (char*)d_ws + off;
        off += (bytes + 255) & ~(size_t)255;
        return p;
    };
    h16*   xh      = (h16*)  carve((size_t)16384 * 4096 * 2);   // x fp16
    h16*   wqT     = (h16*)  carve((size_t)4096 * 4096 * 2);    // wq^T
    h16*   wkvT    = (h16*)  carve((size_t)8192 * 4096 * 2);    // wkv^T
    h16*   woT     = (h16*)  carve((size_t)4096 * 4096 * 2);    // wo^T
    float* queries = (float*)carve((size_t)2048 * 4096 * 4);
    h16*   qn      = (h16*)  carve((size_t)2048 * 4096 * 2);
    h16*   qh      = (h16*)  carve((size_t)2048 * 4096 * 2);
    h16*   kvh     = (h16*)  carve((size_t)16384 * 8192 * 2);
    h16*   oh      = (h16*)  carve((size_t)2048 * 4096 * 2);
    float* tmp     = (float*)xh;  // alias: x fp16 dead after kv GEMM

    // 1. casts / transposes
    cast_f16_kernel<<<(16384L * 4096 / 4) / 256, 256, 0, stream>>>(x, xh);
    transpose_cast_kernel<<<dim3(4096 / 32, 4096 / 32), 256, 0, stream>>>(wq, wqT, 4096, 4096);
    transpose_cast_kernel<<<dim3(8192 / 32, 4096 / 32), 256, 0, stream>>>(wkv, wkvT, 4096, 8192);
    transpose_cast_kernel<<<dim3(4096 / 32, 4096 / 32), 256, 0, stream>>>(wo, woT, 4096, 4096);

    // 2. pool + attention rmsnorm
    pool_rms_kernel<<<2048, 256, 0, stream>>>(x, anw, queries, qn);

    // 3. q = qn @ wq        (M=2048, N=4096, K=4096) -> 128 blocks
    gemm256_kernel<<<8 * 16, 512, 0, stream>>>(
        qn, wqT, qh, nullptr, nullptr, 2048, 4096, 4096, 0);

    // 4. kv = x @ wkv       (M=16384, N=8192, K=4096) -> 2048 blocks
    gemm256_kernel<<<64 * 32, 512, 0, stream>>>(
        xh, wkvT, kvh, nullptr, nullptr, 16384, 8192, 4096, 0);

    // 5. attention per (seg, head)
    attn_kernel<<<dim3(NH, SEGS), 256, 0, stream>>>(qh, kvh, oh);

    // 6. out = o @ wo + queries   (M=2048, N=4096, K=4096), fp32 + residual
    gemm256_kernel<<<8 * 16, 512, 0, stream>>>(
        oh, woT, nullptr, tmp, queries, 2048, 4096, 4096, 1);

    // 7. final rmsnorm -> d_out
    final_rms_kernel<<<2048, 256, 0, stream>>>(tmp, onw, out);
}

// Round 6
// 2014.029 us; speedup vs baseline: 1.0797x; 1.0797x over previous
//
#include <hip/hip_runtime.h>
#include <hip/hip_bf16.h>

typedef _Float16 h16;
typedef _Float16 f16x8 __attribute__((ext_vector_type(8)));
typedef _Float16 f16x4 __attribute__((ext_vector_type(4)));
typedef float f32x4 __attribute__((ext_vector_type(4)));

#define SEGS 32
#define LCTX 512
#define RQ 64
#define NH 32
#define HDIM 128
#define DMODEL 4096

// ---------------- cast fp32 -> fp16 (row-major preserved) ----------------
__global__ __launch_bounds__(256) void cast_f16_kernel(const float* __restrict__ in,
                                                       h16* __restrict__ out) {
    long i = ((long)blockIdx.x * 256 + threadIdx.x) * 4;
    float4 f = *(const float4*)&in[i];
    f16x4 o;
    o[0] = (h16)f.x; o[1] = (h16)f.y; o[2] = (h16)f.z; o[3] = (h16)f.w;
    *(f16x4*)&out[i] = o;
}

// ---------------- transpose + cast: in[K][N] fp32 -> out[N][K] fp16 ----------------
__global__ __launch_bounds__(256) void transpose_cast_kernel(const float* __restrict__ in,
                                                             h16* __restrict__ out,
                                                             int K, int N) {
    __shared__ float tile[32][33];
    int bx = blockIdx.x;  // tiles along N
    int by = blockIdx.y;  // tiles along K
    int tx = threadIdx.x & 31, ty = threadIdx.x >> 5;  // ty 0..7
#pragma unroll
    for (int j = 0; j < 4; j++)
        tile[ty + j * 8][tx] = in[(long)(by * 32 + ty + j * 8) * N + bx * 32 + tx];
    __syncthreads();
#pragma unroll
    for (int j = 0; j < 4; j++)
        out[(long)(bx * 32 + ty + j * 8) * K + by * 32 + tx] = (h16)tile[tx][ty + j * 8];
}

// ---------------- pooling (mean of 8 rows) + rmsnorm -> queries fp32, qn fp16 ----------------
__global__ __launch_bounds__(256) void pool_rms_kernel(const float* __restrict__ x,
                                                       const float* __restrict__ wnorm,
                                                       float* __restrict__ queries,
                                                       h16* __restrict__ qn) {
    const int qi = blockIdx.x;      // 0..2047
    const int t = threadIdx.x;
    const long base = (long)qi * 8 * DMODEL;
    float v[16];
    float ss = 0.f;
#pragma unroll
    for (int i = 0; i < 16; i++) {
        int col = t + i * 256;
        float s = 0.f;
#pragma unroll
        for (int r = 0; r < 8; r++) s += x[base + (long)r * DMODEL + col];
        v[i] = s * 0.125f;
        ss += v[i] * v[i];
    }
#pragma unroll
    for (int d = 1; d < 64; d <<= 1) ss += __shfl_xor(ss, d, 64);
    __shared__ float red[4];
    if ((t & 63) == 0) red[t >> 6] = ss;
    __syncthreads();
    float tot = red[0] + red[1] + red[2] + red[3];
    float scale = rsqrtf(tot / (float)DMODEL + 1e-5f);
#pragma unroll
    for (int i = 0; i < 16; i++) {
        int col = t + i * 256;
        queries[(long)qi * DMODEL + col] = v[i];
        qn[(long)qi * DMODEL + col] = (h16)(v[i] * scale * wnorm[col]);
    }
}

// ============== 256x256x64 8-wave GEMM: C[M][N] = A[M][K] @ Bt[N][K]^T ==============
// fp16 in, MFMA 16x16x32, fp32 acc. EPI==0: fp16 C. EPI==1: fp32 C + residual.
// Round-5 restructure: ONE __syncthreads() per K-tile (its vmcnt/lgkm full-drain is free:
// drained loads are a whole tile old). Inside the tile, ds_reads are issued one phase
// AHEAD of the MFMA cluster that consumes them, with NO manual lgkmcnt/sched_barrier --
// the compiler emits precise counted lgkmcnt, so LDS service overlaps MFMA issue
// (the previous 8-barrier + lgkmcnt(0)-fence lockstep serialized them: 43% MfmaUtil).
// Staging: global_load_lds dwordx4 with both-sides XOR swizzle (byte bits 5,6 ^= rows
// bits 2,3), all 8 next-tile loads issued right after the tile-top barrier.

__device__ __forceinline__ void g2l16(const h16* g, char* l) {
    __builtin_amdgcn_global_load_lds(
        (const __attribute__((address_space(1))) unsigned int*)g,
        (__attribute__((address_space(3))) unsigned int*)l, 16, 0, 0);
}

#define MFMA(d, va, vb) d = __builtin_amdgcn_mfma_f32_16x16x32_f16(va, vb, d, 0, 0, 0)
#define RD(off) (*(const f16x8*)(smem + (off)))

// 16-MFMA cluster for one phase (two 16-row groups MI0/MI1, full 64-col, K=64)
#define CLUSTER(MI0, MI1, x0, x1, x2, x3)                                        \
    __builtin_amdgcn_s_setprio(1);                                               \
    MFMA(acc[MI0][0], x0, b00); MFMA(acc[MI1][0], x2, b00);                      \
    MFMA(acc[MI0][1], x0, b10); MFMA(acc[MI1][1], x2, b10);                      \
    MFMA(acc[MI0][2], x0, b20); MFMA(acc[MI1][2], x2, b20);                      \
    MFMA(acc[MI0][3], x0, b30); MFMA(acc[MI1][3], x2, b30);                      \
    MFMA(acc[MI0][0], x1, b01); MFMA(acc[MI1][0], x3, b01);                      \
    MFMA(acc[MI0][1], x1, b11); MFMA(acc[MI1][1], x3, b11);                      \
    MFMA(acc[MI0][2], x1, b21); MFMA(acc[MI1][2], x3, b21);                      \
    MFMA(acc[MI0][3], x1, b31); MFMA(acc[MI1][3], x3, b31);                      \
    __builtin_amdgcn_s_setprio(0)

// issue ALL 8 prefetch loads for the next tile (buffer po is dead after the barrier)
#define STAGE8()                                                                 \
    do { g2l16(gp0, smem + po + lo0); gp0 += 64;                                 \
         g2l16(gp1, smem + po + lo1); gp1 += 64;                                 \
         g2l16(gp2, smem + po + lo2); gp2 += 64;                                 \
         g2l16(gp3, smem + po + lo3); gp3 += 64;                                 \
         g2l16(gp4, smem + po + lo4); gp4 += 64;                                 \
         g2l16(gp5, smem + po + lo5); gp5 += 64;                                 \
         g2l16(gp6, smem + po + lo6); gp6 += 64;                                 \
         g2l16(gp7, smem + po + lo7); gp7 += 64; } while (0)

__global__ __launch_bounds__(512, 2) void gemm256_kernel(
    const h16* __restrict__ A, const h16* __restrict__ Bt,
    h16* __restrict__ Ch, float* __restrict__ Cf, const float* __restrict__ res,
    int M, int N, int K, int EPI) {
    __shared__ __align__(16) char smem[131072];   // [buf2][A 32K | B 32K]

    const int t = threadIdx.x;
    const int lane = t & 63, w = t >> 6;
    const int wm = w >> 2, wn = w & 3;            // 2 x 4 wave grid
    const int row16 = lane & 15, kq = lane >> 4;

    // XCD-bijective swizzle (grids here are multiples of 8)
    const int nwg = gridDim.x;
    const int id = blockIdx.x;
    const int swz = (id & 7) * (nwg >> 3) + (id >> 3);
    const int NBX = N >> 8;
    const int by = swz / NBX, bx = swz % NBX;
    const long byM = (long)by * 256, bxN = (long)bx * 256;

    // ds-read side swizzle: flip byte bits 5,6 by row bits 2,3
    const unsigned X = ((row16 & 4) ? 32u : 0u) | ((row16 & 8) ? 64u : 0u);
    const unsigned kf0 = (kq * 16) ^ X;           // kstep 0
    const unsigned kf1 = (64 + kq * 16) ^ X;      // kstep 1
    const unsigned aBase = wm * 16384 + row16 * 128;
    const unsigned bBase = 32768u + (wn >> 1) * 16384 + (wn & 1) * 8192 + row16 * 128;

    // staging: per-thread pre-swizzled global source; linear LDS dest (wave-uniform base)
    const unsigned t16x = (unsigned)(t * 16) ^ ((t & 32) ? 32u : 0u) ^ ((t & 64) ? 64u : 0u);
    const int rl = (int)(t16x >> 7);              // row within 64-row load block
    const int chh = (int)((t16x & 127) >> 1);     // h16 col (multiple of 8)
    const h16* gp0 = Bt + (bxN +   0 + rl) * K + chh;
    const h16* gp1 = Bt + (bxN +  64 + rl) * K + chh;
    const h16* gp2 = Bt + (bxN + 128 + rl) * K + chh;
    const h16* gp3 = Bt + (bxN + 192 + rl) * K + chh;
    const h16* gp4 = A  + (byM +   0 + rl) * K + chh;
    const h16* gp5 = A  + (byM + 128 + rl) * K + chh;
    const h16* gp6 = A  + (byM +  64 + rl) * K + chh;
    const h16* gp7 = A  + (byM + 192 + rl) * K + chh;
    const unsigned wb = (unsigned)w * 1024;
    const unsigned lo0 = 32768u + wb,         lo1 = 32768u + 8192 + wb;
    const unsigned lo2 = 49152u + wb,         lo3 = 49152u + 8192 + wb;
    const unsigned lo4 = wb,                  lo5 = 16384u + wb;
    const unsigned lo6 = 8192u + wb,          lo7 = 24576u + wb;

    // prologue: stage tile 0 into buf0 (loop-top __syncthreads drains + publishes it)
    {
        const unsigned po = 0u;
        STAGE8();
    }

    f32x4 acc[8][4] = {};
    const int NT = K >> 6;
    for (int tt = 0; tt < NT; ++tt) {
        const unsigned bo = (tt & 1) ? 0u : 65536u;   // prologue staged into buf0? no: po=0
        // NOTE: prologue staged tile0 into offset 0, so read buffer for tile tt is
        // (tt&1)?65536:0. Keep that mapping:
        const unsigned rb = (tt & 1) ? 65536u : 0u;
        (void)bo;
        const unsigned po = 65536u - rb;
        const unsigned ao = rb + aBase;
        const unsigned bb = rb + bBase;

        // tile-top: full drain (vmcnt: staged loads are ~1 tile old; lgkm: all retired)
        // + barrier. Publishes rb to all waves; makes po safe to overwrite.
        __syncthreads();
        if (tt + 1 < NT) STAGE8();          // prefetch next tile into po

        // B fragments for the whole K-tile (8 ds_read_b128)
        f16x8 b00 = RD(bb + 0    + kf0), b01 = RD(bb + 0    + kf1);
        f16x8 b10 = RD(bb + 2048 + kf0), b11 = RD(bb + 2048 + kf1);
        f16x8 b20 = RD(bb + 4096 + kf0), b21 = RD(bb + 4096 + kf1);
        f16x8 b30 = RD(bb + 6144 + kf0), b31 = RD(bb + 6144 + kf1);
        // phase 0 + phase 1 A fragments up front (compiler leaves ph1 reads outstanding
        // across the ph0 cluster via counted lgkmcnt)
        f16x8 p0a0 = RD(ao + 0     + kf0), p0a1 = RD(ao + 0     + kf1);
        f16x8 p0a2 = RD(ao + 2048  + kf0), p0a3 = RD(ao + 2048  + kf1);
        f16x8 p1a0 = RD(ao + 4096  + kf0), p1a1 = RD(ao + 4096  + kf1);
        f16x8 p1a2 = RD(ao + 6144  + kf0), p1a3 = RD(ao + 6144  + kf1);

        CLUSTER(0, 1, p0a0, p0a1, p0a2, p0a3);          // rows 0-31

        f16x8 p2a0 = RD(ao + 8192  + kf0), p2a1 = RD(ao + 8192  + kf1);
        f16x8 p2a2 = RD(ao + 10240 + kf0), p2a3 = RD(ao + 10240 + kf1);

        CLUSTER(2, 3, p1a0, p1a1, p1a2, p1a3);          // rows 32-63

        f16x8 p3a0 = RD(ao + 12288 + kf0), p3a1 = RD(ao + 12288 + kf1);
        f16x8 p3a2 = RD(ao + 14336 + kf0), p3a3 = RD(ao + 14336 + kf1);

        CLUSTER(4, 5, p2a0, p2a1, p2a2, p2a3);          // rows 64-95
        CLUSTER(6, 7, p3a0, p3a1, p3a2, p3a3);          // rows 96-127
    }

    // epilogue: C/D layout row = quad*4+reg, col = lane&15
    const long wrow = byM + wm * 128 + (lane >> 4) * 4;
    const long wcol = bxN + wn * 64 + row16;
#pragma unroll
    for (int mi = 0; mi < 8; mi++)
#pragma unroll
        for (int n = 0; n < 4; n++)
#pragma unroll
            for (int r = 0; r < 4; r++) {
                long idx = (wrow + mi * 16 + r) * N + wcol + n * 16;
                float v = acc[mi][n][r];
                if (EPI == 0) Ch[idx] = (h16)v;
                else          Cf[idx] = v + res[idx];
            }
}

// ---------------- flash attention: one block per (seg, head) ----------------
// q[2048][4096] fp16, kv[16384][8192] fp16 (k cols 0..4095, v cols 4096..8191)
__global__ __launch_bounds__(256) void attn_kernel(const h16* __restrict__ q,
                                                   const h16* __restrict__ kv,
                                                   h16* __restrict__ o) {
    const int h = blockIdx.x;   // 0..31
    const int s = blockIdx.y;   // 0..31
    const int t = threadIdx.x;
    const int lane = t & 63, w = t >> 6;
    const int row16 = lane & 15, quad = lane >> 4;

    __shared__ h16 kls[32][HDIM + 8];      // [kcol][hd]
    __shared__ h16 vls[HDIM][32 + 8];      // [hd][kcol] (transposed)
    __shared__ h16 pls[4][16][32 + 8];     // per-wave P tile

    f16x8 qf[4];
    {
        const long qrow = (long)(s * RQ + w * 16 + row16) * DMODEL + h * HDIM;
#pragma unroll
        for (int f = 0; f < 4; f++) qf[f] = *(const f16x8*)&q[qrow + f * 32 + quad * 8];
    }
    const float sc = 0.08838834764831845f;  // 1/sqrt(128)
    f32x4 oacc[8] = {};
    float m_i[4], l_i[4];
#pragma unroll
    for (int r = 0; r < 4; r++) { m_i[r] = -1e30f; l_i[r] = 0.f; }

    const long kvbase = (long)s * LCTX * 8192 + h * HDIM;

    for (int kc = 0; kc < LCTX; kc += 32) {
#pragma unroll
        for (int p = 0; p < 2; p++) {
            int u = t + p * 256;
            int r = u >> 4;            // 0..31
            int c8 = (u & 15) * 8;     // 0..120
            *(uint4*)&kls[r][c8] = *(const uint4*)&kv[kvbase + (long)(kc + r) * 8192 + c8];
            f16x8 vv = *(const f16x8*)&kv[kvbase + 4096 + (long)(kc + r) * 8192 + c8];
#pragma unroll
            for (int j = 0; j < 8; j++) vls[c8 + j][r] = vv[j];
        }
        __syncthreads();

        f32x4 st[2] = {};
#pragma unroll
        for (int ct = 0; ct < 2; ct++)
#pragma unroll
            for (int f = 0; f < 4; f++) {
                f16x8 bk = *(const f16x8*)&kls[ct * 16 + row16][f * 32 + quad * 8];
                st[ct] = __builtin_amdgcn_mfma_f32_16x16x32_f16(qf[f], bk, st[ct], 0, 0, 0);
            }

#pragma unroll
        for (int r = 0; r < 4; r++) {
            float s0 = st[0][r] * sc, s1 = st[1][r] * sc;
            float mx = fmaxf(s0, s1);
#pragma unroll
            for (int d = 1; d < 16; d <<= 1) mx = fmaxf(mx, __shfl_xor(mx, d, 64));
            float mn = fmaxf(m_i[r], mx);
            float al = __expf(m_i[r] - mn);
            float p0 = __expf(s0 - mn), p1 = __expf(s1 - mn);
            float ps = p0 + p1;
#pragma unroll
            for (int d = 1; d < 16; d <<= 1) ps += __shfl_xor(ps, d, 64);
            l_i[r] = l_i[r] * al + ps;
            m_i[r] = mn;
#pragma unroll
            for (int ht = 0; ht < 8; ht++) oacc[ht][r] *= al;
            pls[w][quad * 4 + r][row16]      = (h16)p0;
            pls[w][quad * 4 + r][16 + row16] = (h16)p1;
        }
        f16x8 pa = *(const f16x8*)&pls[w][row16][quad * 8];
#pragma unroll
        for (int ht = 0; ht < 8; ht++) {
            f16x8 bv = *(const f16x8*)&vls[ht * 16 + row16][quad * 8];
            oacc[ht] = __builtin_amdgcn_mfma_f32_16x16x32_f16(pa, bv, oacc[ht], 0, 0, 0);
        }
        __syncthreads();
    }
#pragma unroll
    for (int r = 0; r < 4; r++) {
        float inv = 1.0f / l_i[r];
        long orow = (long)(s * RQ + w * 16 + quad * 4 + r) * DMODEL + h * HDIM;
#pragma unroll
        for (int ht = 0; ht < 8; ht++) o[orow + ht * 16 + row16] = (h16)(oacc[ht][r] * inv);
    }
}

// ---------------- final rmsnorm ----------------
__global__ __launch_bounds__(256) void final_rms_kernel(const float* __restrict__ tmp,
                                                        const float* __restrict__ w,
                                                        float* __restrict__ out) {
    const int row = blockIdx.x;
    const int t = threadIdx.x;
    float v[16];
    float ss = 0.f;
#pragma unroll
    for (int i = 0; i < 16; i++) {
        v[i] = tmp[(long)row * DMODEL + t + i * 256];
        ss += v[i] * v[i];
    }
#pragma unroll
    for (int d = 1; d < 64; d <<= 1) ss += __shfl_xor(ss, d, 64);
    __shared__ float red[4];
    if ((t & 63) == 0) red[t >> 6] = ss;
    __syncthreads();
    float tot = red[0] + red[1] + red[2] + red[3];
    float scale = rsqrtf(tot / (float)DMODEL + 1e-5f);
#pragma unroll
    for (int i = 0; i < 16; i++) {
        int col = t + i * 256;
        out[(long)row * DMODEL + col] = v[i] * scale * w[col];
    }
}

extern "C" void kernel_launch(void* const* d_in, const int* in_sizes, int n_in,
                              void* d_out, int out_size, void* d_ws, size_t ws_size,
                              hipStream_t stream) {
    const float* x      = (const float*)d_in[0];  // [16384][4096]
    const float* anw    = (const float*)d_in[1];  // [4096]
    const float* wq     = (const float*)d_in[2];  // [4096][4096]
    const float* wkv    = (const float*)d_in[3];  // [4096][8192]
    const float* wo     = (const float*)d_in[4];  // [4096][4096]
    const float* onw    = (const float*)d_in[5];  // [4096]
    float* out          = (float*)d_out;          // [2048][4096]

    size_t off = 0;
    auto carve = [&](size_t bytes) {
        void* p = (char*)d_ws + off;
        off += (bytes + 255) & ~(size_t)255;
        return p;
    };
    h16*   xh      = (h16*)  carve((size_t)16384 * 4096 * 2);   // x fp16
    h16*   wqT     = (h16*)  carve((size_t)4096 * 4096 * 2);    // wq^T
    h16*   wkvT    = (h16*)  carve((size_t)8192 * 4096 * 2);    // wkv^T
    h16*   woT     = (h16*)  carve((size_t)4096 * 4096 * 2);    // wo^T
    float* queries = (float*)carve((size_t)2048 * 4096 * 4);
    h16*   qn      = (h16*)  carve((size_t)2048 * 4096 * 2);
    h16*   qh      = (h16*)  carve((size_t)2048 * 4096 * 2);
    h16*   kvh     = (h16*)  carve((size_t)16384 * 8192 * 2);
    h16*   oh      = (h16*)  carve((size_t)2048 * 4096 * 2);
    float* tmp     = (float*)xh;  // alias: x fp16 dead after kv GEMM

    // 1. casts / transposes
    cast_f16_kernel<<<(16384L * 4096 / 4) / 256, 256, 0, stream>>>(x, xh);
    transpose_cast_kernel<<<dim3(4096 / 32, 4096 / 32), 256, 0, stream>>>(wq, wqT, 4096, 4096);
    transpose_cast_kernel<<<dim3(8192 / 32, 4096 / 32), 256, 0, stream>>>(wkv, wkvT, 4096, 8192);
    transpose_cast_kernel<<<dim3(4096 / 32, 4096 / 32), 256, 0, stream>>>(wo, woT, 4096, 4096);

    // 2. pool + attention rmsnorm
    pool_rms_kernel<<<2048, 256, 0, stream>>>(x, anw, queries, qn);

    // 3. q = qn @ wq        (M=2048, N=4096, K=4096) -> 128 blocks
    gemm256_kernel<<<8 * 16, 512, 0, stream>>>(
        qn, wqT, qh, nullptr, nullptr, 2048, 4096, 4096, 0);

    // 4. kv = x @ wkv       (M=16384, N=8192, K=4096) -> 2048 blocks
    gemm256_kernel<<<64 * 32, 512, 0, stream>>>(
        xh, wkvT, kvh, nullptr, nullptr, 16384, 8192, 4096, 0);

    // 5. attention per (seg, head)
    attn_kernel<<<dim3(NH, SEGS), 256, 0, stream>>>(qh, kvh, oh);

    // 6. out = o @ wo + queries   (M=2048, N=4096, K=4096), fp32 + residual
    gemm256_kernel<<<8 * 16, 512, 0, stream>>>(
        oh, woT, nullptr, tmp, queries, 2048, 4096, 4096, 1);

    // 7. final rmsnorm -> d_out
    final_rms_kernel<<<2048, 256, 0, stream>>>(tmp, onw, out);
}